// Round 5
// baseline (689.912 us; speedup 1.0000x reference)
//
#include <hip/hip_runtime.h>

#define Bdim 16
#define Cdim 512
#define Hdim 128
#define Wdim 128
#define NS 8
// One WAVE per channel: 64 lanes x 64 float4 = 16384 floats = one channel.
// No LDS, no __syncthreads in the hot kernel: waves are independent linear
// streamers (same memory shape as a copy kernel). 256-thread blocks carry
// 4 waves = 4 channels; grid = 8192/4 = 2048 blocks.

typedef float vfloat4 __attribute__((ext_vector_type(4)));

__global__ __launch_bounds__(256) void chan_reduce(const float* __restrict__ x,
                                                   int* __restrict__ rc,
                                                   float* __restrict__ F) {
    const int tid = threadIdx.x;
    const int lane = tid & 63;
    const int ch = blockIdx.x * 4 + (tid >> 6);   // this wave's channel
    const int b = ch >> 9;                        // ch / Cdim
    const vfloat4* __restrict__ p = (const vfloat4*)(x + ((size_t)ch << 14)) + lane;

    float tsum = 0.f;
    float tmax = -INFINITY;
    // per-16-quad chunk state (statically unrolled -> stays in registers)
    unsigned mask0, mask1, mask2, mask3;     // bit i: quad i's max == chunk max
    unsigned cpk0, cpk1, cpk2, cpk3;         // 2 bits/quad: eq-count-1
    float cm0, cm1, cm2, cm3;                // chunk max

#define CHUNK(cc, MASK, CPK, CMX)                                              \
    {                                                                          \
        unsigned m = 0, cp = 0;                                                \
        float chmax = -INFINITY;                                               \
        _Pragma("unroll") for (int i = 0; i < 16; ++i) {                       \
            const vfloat4 v = __builtin_nontemporal_load(&p[(cc * 16 + i) * 64]); \
            const float mx = fmaxf(fmaxf(v[0], v[1]), fmaxf(v[2], v[3]));      \
            const int c = (v[0] == mx) + (v[1] == mx) + (v[2] == mx) + (v[3] == mx); \
            cp |= (unsigned)(c - 1) << (2 * i);                                \
            const unsigned bit = 1u << i;                                      \
            const bool gt = mx > chmax;                                        \
            const bool eq = mx == chmax;                                       \
            m = gt ? bit : (m | (eq ? bit : 0u));                              \
            chmax = fmaxf(chmax, mx);                                          \
            tsum += (v[0] + v[1]) + (v[2] + v[3]);                             \
        }                                                                      \
        MASK = m; CPK = cp; CMX = chmax;                                       \
        tmax = fmaxf(tmax, chmax);                                             \
    }

    CHUNK(0, mask0, cpk0, cm0)
    CHUNK(1, mask1, cpk1, cm1)
    CHUNK(2, mask2, cpk2, cm2)
    CHUNK(3, mask3, cpk3, cm3)
#undef CHUNK

    // butterfly reduce: every lane ends with the full channel sum & max
    float wsum = tsum, wmax = tmax;
#pragma unroll
    for (int off = 32; off > 0; off >>= 1) {
        wsum += __shfl_xor(wsum, off, 64);
        wmax = fmaxf(wmax, __shfl_xor(wmax, off, 64));
    }

    if (lane == 0) F[ch] = wsum * (1.0f / Wdim);

    // quad q = i_global*64 + lane covers elements [4q,4q+3] -> row = q>>5
    //   = 2*i_global + (lane>>5)
    const int rbase = b * Hdim + (lane >> 5);
#define RECOUNT(cc, MASK, CPK, CMX)                                            \
    if (CMX == wmax) {                                                         \
        unsigned m = MASK;                                                     \
        while (m) {                                                            \
            const int i = __builtin_ctz(m);                                    \
            m &= m - 1;                                                        \
            atomicAdd(&rc[rbase + 2 * (cc * 16 + i)],                          \
                      (int)((CPK >> (2 * i)) & 3u) + 1);                       \
        }                                                                      \
    }

    RECOUNT(0, mask0, cpk0, cm0)
    RECOUNT(1, mask1, cpk1, cm1)
    RECOUNT(2, mask2, cpk2, cm2)
    RECOUNT(3, mask3, cpk3, cm3)
#undef RECOUNT
}

__global__ __launch_bounds__(256) void finalize(const int* __restrict__ rc,
                                                const float* __restrict__ F,
                                                float* __restrict__ out) {
    const int b = blockIdx.x;
    const int tid = threadIdx.x;
    __shared__ int s_rc[Hdim];
    __shared__ int s_Hc[Hdim + 1];
    __shared__ float s_sub[NS];

    if (tid < Hdim) s_rc[tid] = rc[b * Hdim + tid];
    __syncthreads();

    if (tid == 0) {
        s_Hc[0] = 0;
        for (int i = 1; i <= Hdim; ++i) s_Hc[i] = s_Hc[i - 1] + s_rc[i - 1];
        float hks[NS + 1];
        for (int k = 0; k <= NS; ++k) hks[k] = 0.f;
        hks[NS] = (float)Hdim;
        int k = 1;
        for (int j = 1; j <= Hdim - 2; ++j) {
            int t = (k * Cdim) / NS;  // int(k*C/ns)
            if (k < NS && s_Hc[j] <= t && s_Hc[j + 1] > t) {
                hks[k] = (float)j;
                ++k;
            }
        }
        for (int q = 0; q < NS; ++q) s_sub[q] = hks[q + 1] - hks[q];
    }
    __syncthreads();

    // out[b, k*C + c] = F[b, c] / hk_sub[b, k]
    for (int idx = tid; idx < NS * Cdim; idx += 256) {
        int k = idx >> 9;          // idx / Cdim
        int c = idx & (Cdim - 1);
        out[b * (NS * Cdim) + idx] = F[b * Cdim + c] / s_sub[k];
    }
}

extern "C" void kernel_launch(void* const* d_in, const int* in_sizes, int n_in,
                              void* d_out, int out_size, void* d_ws, size_t ws_size,
                              hipStream_t stream) {
    const float* x = (const float*)d_in[0];
    float* out = (float*)d_out;
    int* rc = (int*)d_ws;                                         // B*H ints (8 KB)
    float* F = (float*)((char*)d_ws + Bdim * Hdim * sizeof(int)); // B*C floats (32 KB)

    hipMemsetAsync(rc, 0, Bdim * Hdim * sizeof(int), stream);
    chan_reduce<<<(Bdim * Cdim) / 4, 256, 0, stream>>>(x, rc, F);
    finalize<<<Bdim, 256, 0, stream>>>(rc, F, out);
}

// Round 6
// 654.970 us; speedup vs baseline: 1.0533x; 1.0533x over previous
//
#include <hip/hip_runtime.h>

#define Bdim 16
#define Cdim 512
#define Hdim 128
#define Wdim 128
#define NS 8
#define CPB 4
// per channel: H*W = 16384 floats; per thread: 64 floats = 16 float4
// grid: (B*C)/CPB = 2048 blocks, fully resident at 8 blocks/CU

typedef float vfloat4 __attribute__((ext_vector_type(4)));

__global__ __launch_bounds__(256, 4) void chan_reduce(const float* __restrict__ x,
                                                      int* __restrict__ rc,
                                                      float* __restrict__ F) {
    const int tid = threadIdx.x;
    const int c0 = blockIdx.x * CPB;     // first channel of this block
    const int b = c0 >> 9;               // batch (CPB divides Cdim, never crosses)
    const int rsub = tid >> 5;           // row within each 8-row group
    const int wave = tid >> 6;
    __shared__ float smax[4], ssum[4];

    for (int cc = 0; cc < CPB; ++cc) {
        const int ch = c0 + cc;
        const vfloat4* __restrict__ p = (const vfloat4*)(x + ((size_t)ch << 14));

        // streaming per-thread state: no raw values kept live.
        float tsum = 0.f;
        float tmax = -INFINITY;
        unsigned mask = 0;     // bit i: quad i's max == running thread max
        unsigned cpack = 0;    // 2 bits per quad: (count of elems == quad max) - 1

#pragma unroll
        for (int i = 0; i < 16; ++i) {
            const vfloat4 v = __builtin_nontemporal_load(&p[i * 256 + tid]);
            const float mx = fmaxf(fmaxf(v[0], v[1]), fmaxf(v[2], v[3]));
            const int c = (v[0] == mx) + (v[1] == mx) + (v[2] == mx) + (v[3] == mx);
            cpack |= (unsigned)(c - 1) << (2 * i);
            const unsigned bit = 1u << i;
            const bool gt = mx > tmax;
            const bool eq = mx == tmax;
            mask = gt ? bit : (mask | (eq ? bit : 0u));
            tmax = fmaxf(tmax, mx);
            tsum += (v[0] + v[1]) + (v[2] + v[3]);   // same association as baseline
        }

        // wave (64-lane) reduction; keep thread-local tmax for the match test
        float wsum = tsum, wmax = tmax;
#pragma unroll
        for (int off = 32; off > 0; off >>= 1) {
            wsum += __shfl_down(wsum, off, 64);
            wmax = fmaxf(wmax, __shfl_down(wmax, off, 64));
        }
        if ((tid & 63) == 0) { smax[wave] = wmax; ssum[wave] = wsum; }
        __syncthreads();

        const float bmax = fmaxf(fmaxf(smax[0], smax[1]), fmaxf(smax[2], smax[3]));
        if (tid == 0) {
            F[ch] = (ssum[0] + ssum[1] + ssum[2] + ssum[3]) * (1.0f / Wdim);
        }

        // quads whose max equals the channel max contribute their equal-count
        // to their row. thread's quad #i lives in row i*8 + (tid>>5).
        if (tmax == bmax) {
            unsigned m = mask;
            while (m) {
                const int i = __ffs(m) - 1;
                m &= m - 1;
                atomicAdd(&rc[b * Hdim + i * 8 + rsub],
                          (int)((cpack >> (2 * i)) & 3u) + 1);
            }
        }
        __syncthreads();   // protect smax/ssum before next channel's writes
    }
}

__global__ __launch_bounds__(256) void finalize(const int* __restrict__ rc,
                                                const float* __restrict__ F,
                                                float* __restrict__ out) {
    const int b = blockIdx.x;
    const int tid = threadIdx.x;
    __shared__ int s_rc[Hdim];
    __shared__ int s_Hc[Hdim + 1];
    __shared__ float s_sub[NS];

    if (tid < Hdim) s_rc[tid] = rc[b * Hdim + tid];
    __syncthreads();

    if (tid == 0) {
        s_Hc[0] = 0;
        for (int i = 1; i <= Hdim; ++i) s_Hc[i] = s_Hc[i - 1] + s_rc[i - 1];
        float hks[NS + 1];
        for (int k = 0; k <= NS; ++k) hks[k] = 0.f;
        hks[NS] = (float)Hdim;
        int k = 1;
        for (int j = 1; j <= Hdim - 2; ++j) {
            int t = (k * Cdim) / NS;  // int(k*C/ns)
            if (k < NS && s_Hc[j] <= t && s_Hc[j + 1] > t) {
                hks[k] = (float)j;
                ++k;
            }
        }
        for (int q = 0; q < NS; ++q) s_sub[q] = hks[q + 1] - hks[q];
    }
    __syncthreads();

    // out[b, k*C + c] = F[b, c] / hk_sub[b, k]
    for (int idx = tid; idx < NS * Cdim; idx += 256) {
        int k = idx >> 9;          // idx / Cdim
        int c = idx & (Cdim - 1);
        out[b * (NS * Cdim) + idx] = F[b * Cdim + c] / s_sub[k];
    }
}

extern "C" void kernel_launch(void* const* d_in, const int* in_sizes, int n_in,
                              void* d_out, int out_size, void* d_ws, size_t ws_size,
                              hipStream_t stream) {
    const float* x = (const float*)d_in[0];
    float* out = (float*)d_out;
    int* rc = (int*)d_ws;                                         // B*H ints (8 KB)
    float* F = (float*)((char*)d_ws + Bdim * Hdim * sizeof(int)); // B*C floats (32 KB)

    hipMemsetAsync(rc, 0, Bdim * Hdim * sizeof(int), stream);
    chan_reduce<<<(Bdim * Cdim) / CPB, 256, 0, stream>>>(x, rc, F);
    finalize<<<Bdim, 256, 0, stream>>>(rc, F, out);
}